// Round 1
// baseline (217.255 us; speedup 1.0000x reference)
//
#include <hip/hip_runtime.h>

// ZNCC fused kernel for fixed shape [16, 3, 512, 512] fp32 -> [16, 1, 512, 512] fp32.
// 5x5 box means with zero padding, /25 everywhere (matches lax.reduce_window SAME + /25).
// Box-of-box support is 9x9 -> 4-pixel halo around each 32x32 output tile.

constexpr int Wd = 512, Hd = 512, Cn = 3, Bn = 16;
constexpr int T  = 32;          // output tile
constexpr int HR = T + 8;       // 40: raw tile rows/cols incl halo-4
constexpr int MR = T + 4;       // 36: mean/product region incl halo-2

// LDS layout (floats), with aliasing across phases:
//  sx   @0     40*41 = 1640   raw x tile
//  sy   @1640  40*41 = 1640   raw y tile
//  hx   @3280  40*37 = 1480   horiz 5-sum of x   (later aliased by pxx)
//  hy   @4760  40*37 = 1480   horiz 5-sum of y   (later aliased by pxy)
//  mx   @6240  36*37 = 1332   x mean             (later aliased by hpyy)
//  my   @7572  36*37 = 1332   y mean
//  pyy  @8904  36*37 = 1332
// hpxx aliases sx, hpxy aliases sy (36*33 = 1188 each), hpyy aliases mx.
// Peak = 10236 floats = 40944 B -> 3 blocks/CU LDS-wise.

__global__ __launch_bounds__(256) void zncc_kernel(const float* __restrict__ x,
                                                   const float* __restrict__ y,
                                                   float* __restrict__ out) {
    __shared__ float smem[10236];
    float* sx   = smem;
    float* sy   = smem + 1640;
    float* hx   = smem + 3280;
    float* hy   = smem + 4760;
    float* mx   = smem + 6240;
    float* my   = smem + 7572;
    float* pyy  = smem + 8904;
    float* pxx  = hx;   // alias (hx dead after vertical pass)
    float* pxy  = hy;   // alias
    float* hpxx = sx;   // alias (sx dead after products)
    float* hpxy = sy;   // alias
    float* hpyy = mx;   // alias (mx dead after products)

    const int tid = threadIdx.x;
    const int x0  = blockIdx.x * T;
    const int y0  = blockIdx.y * T;
    const int b   = blockIdx.z;

    float acc[4] = {0.f, 0.f, 0.f, 0.f};

    for (int c = 0; c < Cn; ++c) {
        const float* __restrict__ xp = x + ((size_t)(b * Cn + c)) * (Hd * Wd);
        const float* __restrict__ yp = y + ((size_t)(b * Cn + c)) * (Hd * Wd);

        // Phase A: load 40x40 raw tiles (zero outside image)
        for (int i = tid; i < HR * HR; i += 256) {
            int r  = i / HR, cc = i - r * HR;
            int gy = y0 + r - 4, gx = x0 + cc - 4;
            bool ok = (gy >= 0) & (gy < Hd) & (gx >= 0) & (gx < Wd);
            float vx = 0.f, vy = 0.f;
            if (ok) {
                size_t idx = (size_t)gy * Wd + gx;
                vx = xp[idx];
                vy = yp[idx];
            }
            sx[r * 41 + cc] = vx;
            sy[r * 41 + cc] = vy;
        }
        __syncthreads();

        // Phase B: horizontal 5-sum -> 40 rows x 36 cols
        for (int i = tid; i < HR * MR; i += 256) {
            int r = i / MR, m = i - r * MR;
            const float* p = &sx[r * 41 + m];
            hx[r * 37 + m] = p[0] + p[1] + p[2] + p[3] + p[4];
            const float* q = &sy[r * 41 + m];
            hy[r * 37 + m] = q[0] + q[1] + q[2] + q[3] + q[4];
        }
        __syncthreads();

        // Phase C: vertical 5-sum, /25 -> 36x36 means
        for (int i = tid; i < MR * MR; i += 256) {
            int r = i / MR, m = i - r * MR;
            int o = r * 37 + m;
            mx[o] = (hx[o] + hx[o + 37] + hx[o + 74] + hx[o + 111] + hx[o + 148]) * 0.04f;
            my[o] = (hy[o] + hy[o + 37] + hy[o + 74] + hy[o + 111] + hy[o + 148]) * 0.04f;
        }
        __syncthreads();

        // Phase D: centered products at 36x36 (zero for out-of-image positions —
        // the second box's zero padding applies to the PRODUCT, not (0-mean)^2)
        for (int i = tid; i < MR * MR; i += 256) {
            int r = i / MR, m = i - r * MR;
            int gy = y0 + r - 2, gx = x0 + m - 2;
            float vxx = 0.f, vxy = 0.f, vyy = 0.f;
            if ((gy >= 0) & (gy < Hd) & (gx >= 0) & (gx < Wd)) {
                float vx = sx[(r + 2) * 41 + (m + 2)] - mx[r * 37 + m];
                float vy = sy[(r + 2) * 41 + (m + 2)] - my[r * 37 + m];
                vxx = vx * vx;
                vxy = vx * vy;
                vyy = vy * vy;
            }
            int o = r * 37 + m;
            pxx[o] = vxx;
            pxy[o] = vxy;
            pyy[o] = vyy;
        }
        __syncthreads();

        // Phase E: horizontal 5-sum of products -> 36 rows x 32 cols
        for (int i = tid; i < MR * T; i += 256) {
            int r = i / T, cc = i - r * T;
            int oi = r * 37 + cc;
            int oo = r * 33 + cc;
            hpxx[oo] = pxx[oi] + pxx[oi + 1] + pxx[oi + 2] + pxx[oi + 3] + pxx[oi + 4];
            hpxy[oo] = pxy[oi] + pxy[oi + 1] + pxy[oi + 2] + pxy[oi + 3] + pxy[oi + 4];
            hpyy[oo] = pyy[oi] + pyy[oi + 1] + pyy[oi + 2] + pyy[oi + 3] + pyy[oi + 4];
        }
        __syncthreads();

        // Phase F: vertical 5-sum, /25, NCC, accumulate over channels
        #pragma unroll
        for (int j = 0; j < 4; ++j) {
            int i = tid + j * 256;
            int r = i / T, cc = i - r * T;
            int o = r * 33 + cc;
            float axx = (hpxx[o] + hpxx[o + 33] + hpxx[o + 66] + hpxx[o + 99] + hpxx[o + 132]) * 0.04f;
            float axy = (hpxy[o] + hpxy[o + 33] + hpxy[o + 66] + hpxy[o + 99] + hpxy[o + 132]) * 0.04f;
            float ayy = (hpyy[o] + hpyy[o + 33] + hpyy[o + 66] + hpyy[o + 99] + hpyy[o + 132]) * 0.04f;
            float ncc = axy / (sqrtf(axx) * sqrtf(ayy) + 1e-8f);
            acc[j] += ncc;
        }
        __syncthreads();  // protect hp aliases before next channel's loads
    }

    // Write channel mean: out[b][0][y][x]
    #pragma unroll
    for (int j = 0; j < 4; ++j) {
        int i = tid + j * 256;
        int r = i / T, cc = i - r * T;
        out[(size_t)b * (Hd * Wd) + (size_t)(y0 + r) * Wd + (x0 + cc)] = acc[j] * (1.f / 3.f);
    }
}

extern "C" void kernel_launch(void* const* d_in, const int* in_sizes, int n_in,
                              void* d_out, int out_size, void* d_ws, size_t ws_size,
                              hipStream_t stream) {
    const float* x = (const float*)d_in[0];
    const float* y = (const float*)d_in[1];
    float* out = (float*)d_out;
    dim3 grid(Wd / T, Hd / T, Bn);  // 16 x 16 x 16 tiles/batches
    zncc_kernel<<<grid, 256, 0, stream>>>(x, y, out);
}

// Round 3
// 193.794 us; speedup vs baseline: 1.1211x; 1.1211x over previous
//
#include <hip/hip_runtime.h>

// ZNCC fused streaming kernel. [16,3,512,512] f32 -> [16,1,512,512] f32.
// 5x5 box means, zero pad, /25 everywhere; second box over centered products.
//
// Structure: register-resident vertical rolling sums, horizontal sums in
// registers from overlapping per-lane loads (halo via cache, not LDS).
// Block = 192 threads = 3 waves, one per channel, for one (b, seg, strip).
// Each lane owns NOUT=4 output cols; wave covers a 256-col strip; rows
// streamed in a 32-row segment (+8 halo rows re-streamed).
// LDS: only a 32KB ncc accumulator (ds_add_f32 across the 3 channel waves).

constexpr int W = 512, H = 512, Cn = 3, Bn = 16;
constexpr int HS = 32;       // output rows per segment
constexpr int STRIPW = 256;  // output cols per wave strip
constexpr int NOUT = 4;      // output cols per lane

__device__ __forceinline__ void load_row12(const float* base, bool okA, bool okC,
                                           float* d) {
    // cols [c0, c0+12); A/C float4s may be fully out of image (lane 0 / lane 63 only)
    float4 a = {0.f, 0.f, 0.f, 0.f};
    float4 c = {0.f, 0.f, 0.f, 0.f};
    if (okA) a = *(const float4*)(base);
    float4 b = *(const float4*)(base + 4);
    if (okC) c = *(const float4*)(base + 8);
    d[0] = a.x; d[1] = a.y; d[2]  = a.z; d[3]  = a.w;
    d[4] = b.x; d[5] = b.y; d[6]  = b.z; d[7]  = b.w;
    d[8] = c.x; d[9] = c.y; d[10] = c.z; d[11] = c.w;
}

__global__ __launch_bounds__(192) void zncc_stream(const float* __restrict__ xg,
                                                   const float* __restrict__ yg,
                                                   float* __restrict__ outg) {
    __shared__ float acc[HS * STRIPW];  // 32 KB

    const int tid  = threadIdx.x;
    const int lane = tid & 63;
    const int ch   = tid >> 6;          // wave -> channel
    const int bx   = blockIdx.x;        // seg*2 + strip
    const int seg  = bx >> 1;
    const int strip = bx & 1;
    const int b    = blockIdx.y;
    const int o0   = seg * HS;

    // zero the LDS accumulator
    for (int i = tid; i < HS * STRIPW / 4; i += 192)
        ((float4*)acc)[i] = make_float4(0.f, 0.f, 0.f, 0.f);
    __syncthreads();

    const float* __restrict__ xp = xg + ((size_t)(b * Cn + ch)) * (H * W);
    const float* __restrict__ yp = yg + ((size_t)(b * Cn + ch)) * (H * W);

    const int m0 = strip * STRIPW + lane * NOUT;  // first output col
    const int c0 = m0 - 4;                        // first raw col (12-wide span)
    const bool okA = (c0 >= 0);                   // fails only lane 0, strip 0
    const bool okC = (c0 + 8 < W);                // fails only lane 63, strip 1

    // product-column validity masks (cols m0-2+i)
    float pm[8];
#pragma unroll
    for (int i = 0; i < 8; ++i) {
        int col = m0 - 2 + i;
        pm[i] = (col >= 0 && col < W) ? 1.f : 0.f;
    }

    float vsx[12], vsy[12];                        // rolling vertical 5-row raw sums
    float qxx[5][4], qxy[5][4], qyy[5][4];         // hp queue (5-deep)
    float oxx[4], oxy[4], oyy[4];                  // rolling vertical hp sums
#pragma unroll
    for (int i = 0; i < 12; ++i) { vsx[i] = 0.f; vsy[i] = 0.f; }
#pragma unroll
    for (int s = 0; s < 5; ++s)
#pragma unroll
        for (int j = 0; j < 4; ++j) { qxx[s][j] = 0.f; qxy[s][j] = 0.f; qyy[s][j] = 0.f; }
#pragma unroll
    for (int j = 0; j < 4; ++j) { oxx[j] = 0.f; oxy[j] = 0.f; oyy[j] = 0.f; }

    // iter k: load raw row L = o0-4+k; vsum covers rows L-4..L (center V = L-2);
    // products/hp at row V (k>=4); output row O = L-4 = o0-8+k (k>=8).
    for (int blk = 0; blk < 8; ++blk) {
#pragma unroll
        for (int u = 0; u < 5; ++u) {
            const int k = blk * 5 + u;
            const int L = o0 - 4 + k;

            // subtract row L-5 — ONLY if it was added in this segment's history
            // (first row added is o0-4, i.e. k>=5), and it's a real image row.
            const int Lold = L - 5;
            if (k >= 5 && Lold >= 0) {
                float ox[12], oy[12];
                load_row12(xp + (size_t)Lold * W + c0, okA, okC, ox);
                load_row12(yp + (size_t)Lold * W + c0, okA, okC, oy);
#pragma unroll
                for (int i = 0; i < 12; ++i) { vsx[i] -= ox[i]; vsy[i] -= oy[i]; }
            }
            // add new row L
            if (L >= 0 && L < H) {
                float nx[12], ny[12];
                load_row12(xp + (size_t)L * W + c0, okA, okC, nx);
                load_row12(yp + (size_t)L * W + c0, okA, okC, ny);
#pragma unroll
                for (int i = 0; i < 12; ++i) { vsx[i] += nx[i]; vsy[i] += ny[i]; }
            }

            if (k >= 4) {
                // retire hp row V-5 from rolling output sums (slot u, about to be overwritten)
#pragma unroll
                for (int j = 0; j < 4; ++j) {
                    oxx[j] -= qxx[u][j]; oxy[j] -= qxy[u][j]; oyy[j] -= qyy[u][j];
                }
                const int V = L - 2;
                if (V >= 0 && V < H) {
                    // 25-sums (means*25) at mid cols m0-2+i via incremental h-sum
                    float mx[8], my[8];
                    mx[0] = vsx[0] + vsx[1] + vsx[2] + vsx[3] + vsx[4];
                    my[0] = vsy[0] + vsy[1] + vsy[2] + vsy[3] + vsy[4];
#pragma unroll
                    for (int i = 1; i < 8; ++i) {
                        mx[i] = mx[i - 1] - vsx[i - 1] + vsx[i + 4];
                        my[i] = my[i - 1] - vsy[i - 1] + vsy[i + 4];
                    }
                    // center row raw (re-read; L1 hot — loaded 2 iters ago)
                    float cx[12], cyv[12];
                    load_row12(xp + (size_t)V * W + c0, okA, okC, cx);
                    load_row12(yp + (size_t)V * W + c0, okA, okC, cyv);

                    float pxx[8], pxy[8], pyy[8];
#pragma unroll
                    for (int i = 0; i < 8; ++i) {
                        float xc = (cx[i + 2]  - mx[i] * 0.04f) * pm[i];
                        float yc = (cyv[i + 2] - my[i] * 0.04f) * pm[i];
                        pxx[i] = xc * xc; pxy[i] = xc * yc; pyy[i] = yc * yc;
                    }
                    // horizontal 5-sum of products -> 4 outputs; push + add to rolling sums
                    float h;
                    h = pxx[0] + pxx[1] + pxx[2] + pxx[3] + pxx[4];
                    qxx[u][0] = h; oxx[0] += h;
#pragma unroll
                    for (int j = 1; j < 4; ++j) {
                        h = h - pxx[j - 1] + pxx[j + 4]; qxx[u][j] = h; oxx[j] += h;
                    }
                    h = pxy[0] + pxy[1] + pxy[2] + pxy[3] + pxy[4];
                    qxy[u][0] = h; oxy[0] += h;
#pragma unroll
                    for (int j = 1; j < 4; ++j) {
                        h = h - pxy[j - 1] + pxy[j + 4]; qxy[u][j] = h; oxy[j] += h;
                    }
                    h = pyy[0] + pyy[1] + pyy[2] + pyy[3] + pyy[4];
                    qyy[u][0] = h; oyy[0] += h;
#pragma unroll
                    for (int j = 1; j < 4; ++j) {
                        h = h - pyy[j - 1] + pyy[j + 4]; qyy[u][j] = h; oyy[j] += h;
                    }
                } else {
                    // padding row: products are zero
#pragma unroll
                    for (int j = 0; j < 4; ++j) { qxx[u][j] = 0.f; qxy[u][j] = 0.f; qyy[u][j] = 0.f; }
                }

                if (k >= 8) {
                    const int r = k - 8;  // output row within segment
#pragma unroll
                    for (int j = 0; j < 4; ++j) {
                        // ncc = (Sxy/25) / (sqrt(Sxx/25)*sqrt(Syy/25) + 1e-8)
                        //     = Sxy / (sqrt(Sxx*Syy) + 25e-8)
                        float rad = fmaxf(oxx[j] * oyy[j], 0.f);  // guard rolling drift
                        float s = sqrtf(rad) + 2.5e-7f;
                        float ncc = oxy[j] * __builtin_amdgcn_rcpf(s);
                        atomicAdd(&acc[r * STRIPW + lane * NOUT + j], ncc);
                    }
                }
            }
        }
    }

    __syncthreads();
    // writeout: mean over 3 channels
    const float inv3 = 1.f / 3.f;
    float* op = outg + (size_t)b * (H * W);
    for (int i = tid; i < HS * STRIPW / 4; i += 192) {
        float4 v = ((const float4*)acc)[i];
        v.x *= inv3; v.y *= inv3; v.z *= inv3; v.w *= inv3;
        int r = i / (STRIPW / 4);
        int c4 = i - r * (STRIPW / 4);
        *(float4*)(op + (size_t)(o0 + r) * W + strip * STRIPW + c4 * 4) = v;
    }
}

extern "C" void kernel_launch(void* const* d_in, const int* in_sizes, int n_in,
                              void* d_out, int out_size, void* d_ws, size_t ws_size,
                              hipStream_t stream) {
    const float* x = (const float*)d_in[0];
    const float* y = (const float*)d_in[1];
    float* out = (float*)d_out;
    dim3 grid((H / HS) * (W / STRIPW), Bn);  // 32 x 16 blocks
    zncc_stream<<<grid, 192, 0, stream>>>(x, y, out);
}